// Round 7
// baseline (1006.010 us; speedup 1.0000x reference)
//
#include <hip/hip_runtime.h>
#include <hip/hip_cooperative_groups.h>

#define NN 50000
#define E0 200000
#define E2 400000
#define NGROUPS ((NN + 7) / 8)      // 6250
#define NCHUNK  ((NN + 255) / 256)  // 196
#define NTILES  ((NN + 63) / 64)    // 782

typedef __attribute__((ext_vector_type(8))) short short8;
typedef __attribute__((ext_vector_type(4))) float f32x4;

namespace cg = cooperative_groups;

__device__ __forceinline__ float eluf(float x) { return x > 0.0f ? x : expm1f(x); }
__device__ __forceinline__ float sigmoidf(float x) { return 1.0f / (1.0f + expf(-x)); }
__device__ __forceinline__ unsigned rne_bf16(float x) {
    unsigned u = __float_as_uint(x);
    return (u + 0x7fffu + ((u >> 16) & 1u)) >> 16;
}

// LDS union kept small (<=8.9 KB) so occupancy is never LDS-limited.
struct SMemGemm { unsigned short whi[16 * 136]; unsigned short wlo[16 * 136]; };   // 8704 B
struct SMemY8   { float wrs[32 * 33]; float wls[9]; float xcs[8][96]; float ws1[192]; float wt[192]; }; // 8868 B
struct SMemSpec { float W[32 * 33]; float us[32]; float vs[32]; float tmp[32]; float scal; };
struct SMemScan { int s[256]; };
union SMem { SMemGemm g; SMemY8 y; SMemSpec sp; SMemScan sc; };

struct Params {
    const float* x; const int* ei;
    const float *W1, *b1, *W2, *b2, *Wl, *Wr, *eps, *Wsh, *Wwt;
    float* out;
    float* xc; float4* meta; unsigned* yp01; unsigned short* yp2;
    float *aR, *aC, *wR, *wC, *deg, *dinv, *Wl_n, *Wr_n;
    int *cnt, *start, *fill, *eslot, *bsum, *bofs;
    unsigned short *w1hi, *w1lo, *w2hi, *w2lo;
};

// ---------- MFMA GEMM phase: out = act(X[M,K] @ W[N,K]^T + b), split-bf16, 16-row B stages
template<int K, int N, bool ELU>
__device__ void gemm_phase(const float* __restrict__ X, const unsigned short* __restrict__ Whi,
                           const unsigned short* __restrict__ Wlo, const float* __restrict__ bias,
                           float* __restrict__ out, int bid, int nb, int tid, SMem* sm) {
    constexpr int KP = K + 8;          // row stride in shorts (16B-aligned rows)
    constexpr int KS = K / 32;
    constexpr int CT = N / 32;
    const int wave = tid >> 6, lane = tid & 63;
    const int quad = lane >> 4, r16 = lane & 15;
    for (int t = bid; t < NTILES; t += nb) {
        long m = (long)t * 64 + wave * 16 + r16;
        long mc = m < NN ? m : NN - 1;   // clamp OOB A-loads; stores guarded
        const float* xrow = X + mc * K + quad * 8;
        short8 ah[KS], al[KS];
#pragma unroll
        for (int ks = 0; ks < KS; ++ks) {
            const float4* xp = (const float4*)(xrow + ks * 32);
            float4 p0 = xp[0], p1 = xp[1];
            float xv[8] = {p0.x, p0.y, p0.z, p0.w, p1.x, p1.y, p1.z, p1.w};
#pragma unroll
            for (int j = 0; j < 8; ++j) {
                unsigned h = rne_bf16(xv[j]);
                ah[ks][j] = (short)h;
                al[ks][j] = (short)rne_bf16(xv[j] - __uint_as_float(h << 16));
            }
        }
#pragma unroll
        for (int ct = 0; ct < CT; ++ct) {
            f32x4 accs[2];
#pragma unroll
            for (int sub = 0; sub < 2; ++sub) {
                __syncthreads();
                for (int i = tid; i < 16 * K / 2; i += 256) {
                    int e = i * 2, r = e / K, c = e % K;
                    int gp = (ct * 32 + sub * 16 + r) * (K / 2) + (c >> 1);
                    unsigned vh = ((const unsigned*)Whi)[gp];
                    unsigned vl = ((const unsigned*)Wlo)[gp];
                    *(unsigned*)&sm->g.whi[r * KP + c] = vh;
                    *(unsigned*)&sm->g.wlo[r * KP + c] = vl;
                }
                __syncthreads();
                f32x4 a0 = {0.f, 0.f, 0.f, 0.f};
#pragma unroll
                for (int ks = 0; ks < KS; ++ks) {
                    int ro = r16 * KP + ks * 32 + quad * 8;
                    short8 bh = *(const short8*)&sm->g.whi[ro];
                    short8 bl = *(const short8*)&sm->g.wlo[ro];
                    a0 = __builtin_amdgcn_mfma_f32_16x16x32_bf16(ah[ks], bh, a0, 0, 0, 0);
                    a0 = __builtin_amdgcn_mfma_f32_16x16x32_bf16(al[ks], bh, a0, 0, 0, 0);
                    a0 = __builtin_amdgcn_mfma_f32_16x16x32_bf16(ah[ks], bl, a0, 0, 0, 0);
                }
                accs[sub] = a0;
            }
            // C/D: col = lane&15, row = quad*4 + reg [m89-verified]
            long mbase = (long)t * 64 + wave * 16 + quad * 4;
#pragma unroll
            for (int tt = 0; tt < 2; ++tt) {
                float b = bias[ct * 32 + tt * 16 + r16];
#pragma unroll
                for (int rr = 0; rr < 4; ++rr) {
                    long mm = mbase + rr;
                    if (mm < NN) {
                        float v = accs[tt][rr] + b;
                        if (ELU) v = eluf(v);
                        out[mm * N + ct * 32 + tt * 16 + r16] = v;
                    }
                }
            }
        }
    }
}

// ---------- spectral norm (one block; 256 threads, guards to 32)
__device__ void spectral_dev(int l, int t, const float* __restrict__ Wl_in,
                             const float* __restrict__ Wr_in,
                             float* __restrict__ Wl_out, float* __restrict__ Wr_out, SMem* sm) {
    SMemSpec& S = sm->sp;
    for (int i = t; i < 1024; i += 256) S.W[(i >> 5) * 33 + (i & 31)] = Wr_in[l * 1024 + i];
    if (t < 32) S.us[t] = 0.17677669529663688f;
    __syncthreads();
    for (int it = 0; it < 20; ++it) {
        if (t < 32) { float a = 0; for (int r = 0; r < 32; ++r) a = fmaf(S.W[r * 33 + t], S.us[r], a); S.tmp[t] = a; }
        __syncthreads();
        if (t == 0) { float s = 0; for (int c = 0; c < 32; ++c) s += S.tmp[c] * S.tmp[c]; S.scal = 1.0f / (sqrtf(s) + 1e-12f); }
        __syncthreads();
        if (t < 32) S.vs[t] = S.tmp[t] * S.scal;
        __syncthreads();
        if (t < 32) { float a = 0; for (int c = 0; c < 32; ++c) a = fmaf(S.W[t * 33 + c], S.vs[c], a); S.tmp[t] = a; }
        __syncthreads();
        if (t == 0) { float s = 0; for (int r = 0; r < 32; ++r) s += S.tmp[r] * S.tmp[r]; S.scal = 1.0f / (sqrtf(s) + 1e-12f); }
        __syncthreads();
        if (t < 32) S.us[t] = S.tmp[t] * S.scal;
        __syncthreads();
    }
    if (t < 32) { float a = 0; for (int r = 0; r < 32; ++r) a = fmaf(S.W[r * 33 + t], S.us[r], a); S.tmp[t] = a; }
    __syncthreads();
    if (t == 0) {
        float s = 0; for (int c = 0; c < 32; ++c) s += S.tmp[c] * S.tmp[c];
        S.scal = (sqrtf(s) + 1e-12f) / s;   // 1/sigma
    }
    __syncthreads();
    for (int i = t; i < 1024; i += 256) Wr_out[l * 1024 + i] = S.W[(i >> 5) * 33 + (i & 31)] * S.scal;
    if (t == 0) {
        float M[9];
        for (int i = 0; i < 9; ++i) M[i] = Wl_in[l * 9 + i];
        float u[3] = {0.5773502691896258f, 0.5773502691896258f, 0.5773502691896258f};
        float v[3], u2[3];
        for (int it = 0; it < 20; ++it) {
            float s = 0;
            for (int c = 0; c < 3; ++c) { v[c] = M[c] * u[0] + M[3 + c] * u[1] + M[6 + c] * u[2]; s += v[c] * v[c]; }
            float inv = 1.0f / (sqrtf(s) + 1e-12f);
            for (int c = 0; c < 3; ++c) v[c] *= inv;
            s = 0;
            for (int r = 0; r < 3; ++r) { u2[r] = M[r * 3] * v[0] + M[r * 3 + 1] * v[1] + M[r * 3 + 2] * v[2]; s += u2[r] * u2[r]; }
            inv = 1.0f / (sqrtf(s) + 1e-12f);
            for (int r = 0; r < 3; ++r) u[r] = u2[r] * inv;
        }
        float s = 0;
        for (int c = 0; c < 3; ++c) { v[c] = M[c] * u[0] + M[3 + c] * u[1] + M[6 + c] * u[2]; s += v[c] * v[c]; }
        float inv = (sqrtf(s) + 1e-12f) / s;
        for (int i = 0; i < 9; ++i) Wl_out[l * 9 + i] = M[i] * inv;
    }
}

__global__ __launch_bounds__(256, 4) void k_mega(Params p) {
    cg::grid_group grid = cg::this_grid();
    const int tid = threadIdx.x;
    const int bid = blockIdx.x;
    const int G = gridDim.x;
    const int gtid = bid * 256 + tid;
    const int GT = G * 256;
    __shared__ SMem sm;
    const int* row = p.ei;
    const int* col = p.ei + E2;

    // ph0: split weights; zero cnt/fill/deg
    for (int i = gtid; i < 96 * 128; i += GT) {
        float v = p.W1[i];
        unsigned h = rne_bf16(v);
        p.w1hi[i] = (unsigned short)h;
        p.w1lo[i] = (unsigned short)rne_bf16(v - __uint_as_float(h << 16));
    }
    for (int i = gtid; i < 32 * 96; i += GT) {
        float v = p.W2[i];
        unsigned h = rne_bf16(v);
        p.w2hi[i] = (unsigned short)h;
        p.w2lo[i] = (unsigned short)rne_bf16(v - __uint_as_float(h << 16));
    }
    for (int i = gtid; i < NN; i += GT) { p.cnt[i] = 0; p.fill[i] = 0; p.deg[i] = 0.0f; }
    grid.sync();

    // ph1: blocks 0-1 spectral; blocks 2+ lin1 + edge histogram
    if (bid < 2) {
        spectral_dev(bid, tid, p.Wl, p.Wr, p.Wl_n, p.Wr_n, &sm);
    } else {
        gemm_phase<128, 96, true>(p.x, p.w1hi, p.w1lo, p.b1, p.xc, bid - 2, G - 2, tid, &sm);
        for (int e = (bid - 2) * 256 + tid; e < E2; e += (G - 2) * 256)
            atomicAdd(&p.cnt[row[e]], 1);
    }
    grid.sync();

    // ph2: per-chunk exclusive scan
    for (int ch = bid; ch < NCHUNK; ch += G) {
        int i = ch * 256 + tid;
        int v = (i < NN) ? p.cnt[i] : 0;
        sm.sc.s[tid] = v;
        __syncthreads();
        for (int off = 1; off < 256; off <<= 1) {
            int add = (tid >= off) ? sm.sc.s[tid - off] : 0;
            __syncthreads();
            sm.sc.s[tid] += add;
            __syncthreads();
        }
        if (i < NN) p.start[i] = sm.sc.s[tid] - v;
        if (tid == 255) p.bsum[ch] = sm.sc.s[255];
        __syncthreads();
    }
    grid.sync();

    // ph3: chunk-sum scan (block 0)
    if (bid == 0) {
        int v = (tid < NCHUNK) ? p.bsum[tid] : 0;
        sm.sc.s[tid] = v;
        __syncthreads();
        for (int off = 1; off < 256; off <<= 1) {
            int add = (tid >= off) ? sm.sc.s[tid - off] : 0;
            __syncthreads();
            sm.sc.s[tid] += add;
            __syncthreads();
        }
        if (tid < NCHUNK) p.bofs[tid] = sm.sc.s[tid] - v;
    }
    grid.sync();

    // ph4
    for (int i = gtid; i < NN; i += GT) p.start[i] += p.bofs[i >> 8];
    grid.sync();

    // ph5: CSR slot assignment
    for (int e = gtid; e < E2; e += GT) {
        int u = row[e];
        p.eslot[e] = p.start[u] + atomicAdd(&p.fill[u], 1);
    }
    grid.sync();

    for (int l = 0; l < 2; ++l) {
        // ph6: y (packed bf16) + node projections; zero deg
        for (int i = gtid; i < NN; i += GT) p.deg[i] = 0.0f;
        for (int i = tid; i < 1024; i += 256) sm.y.wrs[(i >> 5) * 33 + (i & 31)] = p.Wr_n[l * 1024 + i];
        if (tid < 9) sm.y.wls[tid] = p.Wl_n[l * 9 + tid];
        if (tid < 192) {
            sm.y.ws1[tid] = p.Wsh[(l * 3 + 1) * 192 + tid];  // only row 1 of W_sheaf survives Cayley (D=2)
            sm.y.wt[tid]  = p.Wwt[l * 192 + tid];
        }
        for (int gi = bid; gi < NGROUPS; gi += G) {
            int n0 = gi * 8;
            __syncthreads();
            for (int i = tid; i < 768; i += 256) {
                int n = n0 + i / 96;
                sm.y.xcs[i / 96][i % 96] = (n < NN) ? p.xc[n * 96 + i % 96] : 0.0f;
            }
            __syncthreads();
            int node = tid >> 5, c = tid & 31;
            int n = n0 + node;
            float a1 = 0, a2 = 0, a3 = 0, a4 = 0;
#pragma unroll
            for (int j = 0; j < 3; ++j) {
                int k = j * 32 + c;
                float xv = sm.y.xcs[node][k];
                a1 = fmaf(xv, sm.y.ws1[k], a1);
                a2 = fmaf(xv, sm.y.ws1[96 + k], a2);
                a3 = fmaf(xv, sm.y.wt[k], a3);
                a4 = fmaf(xv, sm.y.wt[96 + k], a4);
            }
#pragma unroll
            for (int off = 16; off; off >>= 1) {
                a1 += __shfl_xor(a1, off);
                a2 += __shfl_xor(a2, off);
                a3 += __shfl_xor(a3, off);
                a4 += __shfl_xor(a4, off);
            }
            if (c == 0 && n < NN) { p.aR[n] = a1; p.aC[n] = a2; p.wR[n] = a3; p.wC[n] = a4; }
            if (n < NN) {
                float t0 = 0, t1 = 0, t2 = 0;
                const float* wr = &sm.y.wrs[c * 33];
                const float* xr = sm.y.xcs[node];
#pragma unroll
                for (int h = 0; h < 32; ++h) {
                    float w = wr[h];
                    t0 = fmaf(xr[h], w, t0);
                    t1 = fmaf(xr[32 + h], w, t1);
                    t2 = fmaf(xr[64 + h], w, t2);
                }
                float o0 = sm.y.wls[0] * t0 + sm.y.wls[1] * t1 + sm.y.wls[2] * t2;
                float o1 = sm.y.wls[3] * t0 + sm.y.wls[4] * t1 + sm.y.wls[5] * t2;
                float o2 = sm.y.wls[6] * t0 + sm.y.wls[7] * t1 + sm.y.wls[8] * t2;
                p.yp01[n * 32 + c] = rne_bf16(o0) | (rne_bf16(o1) << 16);
                p.yp2[n * 32 + c]  = (unsigned short)rne_bf16(o2);
            }
        }
        grid.sync();

        // ph7: edge coefficients (E0; reverse by symmetry) + degree
        for (int e = gtid; e < E0; e += GT) {
            int u = row[e], v = col[e];
            float a_e = tanhf(p.aR[u] + p.aC[v]);
            float a_r = tanhf(p.aR[v] + p.aC[u]);
            float wd_e = sigmoidf(p.wR[u] + p.wC[v]);
            float wd_r = sigmoidf(p.wR[v] + p.wC[u]);
            float w = wd_e * wd_r;
            float w2 = w * w;
            float ie = 1.0f / (1.0f + a_e * a_e), ir = 1.0f / (1.0f + a_r * a_r);
            float ce = (1.0f - a_e * a_e) * ie, se = 2.0f * a_e * ie;
            float cr = (1.0f - a_r * a_r) * ir, sr = 2.0f * a_r * ir;
            float C = ce * cr + se * sr;   // T_e = Q_e^T Q_rev ; T_rev = T^T -> (C,-S)
            float S = ce * sr - se * cr;
            p.meta[p.eslot[e]]      = make_float4(C,  S, w2, __int_as_float(v));
            p.meta[p.eslot[e + E0]] = make_float4(C, -S, w2, __int_as_float(u));
            atomicAdd(&p.deg[u], w2);
            atomicAdd(&p.deg[v], w2);
        }
        grid.sync();

        // ph8: dinv
        for (int i = gtid; i < NN; i += GT) {
            float d = p.deg[i];
            p.dinv[i] = d > 0.0f ? rsqrtf(fmaxf(d, 1e-30f)) : 0.0f;
        }
        grid.sync();

        // ph9: gather + residual update
        for (int gi = bid; gi < NGROUPS; gi += G) {
            int node = tid >> 5, c = tid & 31;
            int n = gi * 8 + node;
            if (n < NN) {
                int s0 = p.start[n], ec = p.cnt[n];
                float du = p.dinv[n];
                float acc0 = 0, acc1 = 0, acc2 = 0;
                for (int bs = 0; bs < ec; bs += 32) {
                    int nb2 = min(32, ec - bs);
                    float CC = 0, SS = 0, cnl = 0;
                    int vj = 0;
                    if (c < nb2) {
                        float4 mt = p.meta[s0 + bs + c];
                        vj = __float_as_int(mt.w);
                        cnl = mt.z * du * p.dinv[vj];
                        CC = cnl * mt.x;
                        SS = cnl * mt.y;
                    }
                    for (int j = 0; j < nb2; ++j) {
                        float Cj = __shfl(CC, j, 32);
                        float Sj = __shfl(SS, j, 32);
                        float cj = __shfl(cnl, j, 32);
                        int v = __shfl(vj, j, 32);
                        unsigned u01 = p.yp01[v * 32 + c];
                        unsigned u2v = (unsigned)p.yp2[v * 32 + c];
                        float y0 = __uint_as_float(u01 << 16);
                        float y1 = __uint_as_float(u01 & 0xffff0000u);
                        float y2 = __uint_as_float(u2v << 16);
                        acc0 = fmaf(Cj, y0, acc0);
                        acc0 = fmaf(-Sj, y1, acc0);
                        acc1 = fmaf(Sj, y0, acc1);
                        acc1 = fmaf(Cj, y1, acc1);
                        acc2 = fmaf(cj, y2, acc2);
                    }
                }
                float diag = du > 0.0f ? 1.0f : 0.0f;
                unsigned u01 = p.yp01[n * 32 + c];
                unsigned u2v = (unsigned)p.yp2[n * 32 + c];
                float oy0 = __uint_as_float(u01 << 16);
                float oy1 = __uint_as_float(u01 & 0xffff0000u);
                float oy2 = __uint_as_float(u2v << 16);
                float c0 = 1.0f + tanhf(p.eps[l * 3 + 0]);
                float c1 = 1.0f + tanhf(p.eps[l * 3 + 1]);
                float c2 = 1.0f + tanhf(p.eps[l * 3 + 2]);
                int base = n * 96 + c;
                float z0 = eluf(diag * oy0 - acc0);
                float z1 = eluf(diag * oy1 - acc1);
                float z2 = eluf(diag * oy2 - acc2);
                p.xc[base]      = c0 * p.xc[base]      - z0;
                p.xc[base + 32] = c1 * p.xc[base + 32] - z1;
                p.xc[base + 64] = c2 * p.xc[base + 64] - z2;
            }
        }
        grid.sync();
    }

    // ph10: lin2 -> out
    gemm_phase<96, 32, false>(p.xc, p.w2hi, p.w2lo, p.b2, p.out, bid, G, tid, &sm);
}

// ================= fallback multi-kernel path (round-5, proven) =================
__global__ __launch_bounds__(256) void f_splitw(const float* __restrict__ W, int n,
                                                unsigned short* __restrict__ hi,
                                                unsigned short* __restrict__ lo) {
    int i = blockIdx.x * 256 + threadIdx.x;
    if (i >= n) return;
    float x = W[i];
    unsigned h = rne_bf16(x);
    hi[i] = (unsigned short)h;
    lo[i] = (unsigned short)rne_bf16(x - __uint_as_float(h << 16));
}

template<int K, int N, bool ELU>
__global__ __launch_bounds__(256) void f_gemm(const float* __restrict__ X,
                                              const unsigned short* __restrict__ Whi,
                                              const unsigned short* __restrict__ Wlo,
                                              const float* __restrict__ bias,
                                              float* __restrict__ out) {
    __shared__ SMem sm;
    gemm_phase<K, N, ELU>(X, Whi, Wlo, bias, out, blockIdx.x, gridDim.x, threadIdx.x, &sm);
}

__global__ __launch_bounds__(256) void f_spectral(const float* __restrict__ Wl_in,
                                                  const float* __restrict__ Wr_in,
                                                  float* __restrict__ Wl_out,
                                                  float* __restrict__ Wr_out) {
    __shared__ SMem sm;
    spectral_dev(blockIdx.x, threadIdx.x, Wl_in, Wr_in, Wl_out, Wr_out, &sm);
}

__global__ __launch_bounds__(256) void f_zero(int* cnt, int* fill, float* deg) {
    int i = blockIdx.x * 256 + threadIdx.x;
    if (i < NN) { cnt[i] = 0; fill[i] = 0; deg[i] = 0.0f; }
}
__global__ __launch_bounds__(256) void f_hist(const int* __restrict__ row, int* __restrict__ cnt) {
    int e = blockIdx.x * 256 + threadIdx.x;
    if (e < E2) atomicAdd(&cnt[row[e]], 1);
}
__global__ __launch_bounds__(256) void f_scan1(const int* __restrict__ cnt, int* __restrict__ start,
                                               int* __restrict__ bsum) {
    __shared__ int s[256];
    int b = blockIdx.x, t = threadIdx.x;
    int i = b * 256 + t;
    int v = (i < NN) ? cnt[i] : 0;
    s[t] = v;
    __syncthreads();
    for (int off = 1; off < 256; off <<= 1) {
        int add = (t >= off) ? s[t - off] : 0;
        __syncthreads();
        s[t] += add;
        __syncthreads();
    }
    if (i < NN) start[i] = s[t] - v;
    if (t == 255) bsum[b] = s[t];
}
__global__ __launch_bounds__(256) void f_scan2(const int* __restrict__ bsum, int* __restrict__ bofs, int nb) {
    __shared__ int s[256];
    int t = threadIdx.x;
    int v = (t < nb) ? bsum[t] : 0;
    s[t] = v;
    __syncthreads();
    for (int off = 1; off < 256; off <<= 1) {
        int add = (t >= off) ? s[t - off] : 0;
        __syncthreads();
        s[t] += add;
        __syncthreads();
    }
    if (t < nb) bofs[t] = s[t] - v;
}
__global__ __launch_bounds__(256) void f_scan3(int* __restrict__ start, const int* __restrict__ bofs) {
    int i = blockIdx.x * 256 + threadIdx.x;
    if (i < NN) start[i] += bofs[i >> 8];
}
__global__ __launch_bounds__(256) void f_fill(const int* __restrict__ row, const int* __restrict__ start,
                                              int* __restrict__ fill, int* __restrict__ eslot) {
    int e = blockIdx.x * 256 + threadIdx.x;
    if (e >= E2) return;
    int u = row[e];
    eslot[e] = start[u] + atomicAdd(&fill[u], 1);
}

__global__ __launch_bounds__(256) void f_y8(const float* __restrict__ xc,
                                            const float* __restrict__ Wl, const float* __restrict__ Wr,
                                            const float* __restrict__ Wsh, const float* __restrict__ Wwt,
                                            int layer, unsigned* __restrict__ yp01,
                                            unsigned short* __restrict__ yp2,
                                            float* __restrict__ aR, float* __restrict__ aC,
                                            float* __restrict__ wR, float* __restrict__ wC,
                                            float* __restrict__ deg) {
    __shared__ SMem smu;
    SMemY8& sy = smu.y;
    int tid = threadIdx.x;
    int n0 = blockIdx.x * 8;
    if (tid < 8) { int nz = n0 + tid; if (nz < NN) deg[nz] = 0.0f; }
    for (int i = tid; i < 1024; i += 256) sy.wrs[(i >> 5) * 33 + (i & 31)] = Wr[i];
    if (tid < 9) sy.wls[tid] = Wl[tid];
    if (tid < 192) {
        sy.ws1[tid] = Wsh[(layer * 3 + 1) * 192 + tid];
        sy.wt[tid]  = Wwt[layer * 192 + tid];
    }
    for (int i = tid; i < 768; i += 256) {
        int n = n0 + i / 96;
        sy.xcs[i / 96][i % 96] = (n < NN) ? xc[n * 96 + i % 96] : 0.0f;
    }
    __syncthreads();
    int node = tid >> 5, c = tid & 31;
    int n = n0 + node;
    float a1 = 0, a2 = 0, a3 = 0, a4 = 0;
#pragma unroll
    for (int j = 0; j < 3; ++j) {
        int k = j * 32 + c;
        float xv = sy.xcs[node][k];
        a1 = fmaf(xv, sy.ws1[k], a1);
        a2 = fmaf(xv, sy.ws1[96 + k], a2);
        a3 = fmaf(xv, sy.wt[k], a3);
        a4 = fmaf(xv, sy.wt[96 + k], a4);
    }
#pragma unroll
    for (int off = 16; off; off >>= 1) {
        a1 += __shfl_xor(a1, off);
        a2 += __shfl_xor(a2, off);
        a3 += __shfl_xor(a3, off);
        a4 += __shfl_xor(a4, off);
    }
    if (c == 0 && n < NN) { aR[n] = a1; aC[n] = a2; wR[n] = a3; wC[n] = a4; }
    if (n < NN) {
        float t0 = 0, t1 = 0, t2 = 0;
        const float* wr = &sy.wrs[c * 33];
        const float* xr = sy.xcs[node];
#pragma unroll
        for (int h = 0; h < 32; ++h) {
            float w = wr[h];
            t0 = fmaf(xr[h], w, t0);
            t1 = fmaf(xr[32 + h], w, t1);
            t2 = fmaf(xr[64 + h], w, t2);
        }
        float o0 = sy.wls[0] * t0 + sy.wls[1] * t1 + sy.wls[2] * t2;
        float o1 = sy.wls[3] * t0 + sy.wls[4] * t1 + sy.wls[5] * t2;
        float o2 = sy.wls[6] * t0 + sy.wls[7] * t1 + sy.wls[8] * t2;
        yp01[n * 32 + c] = rne_bf16(o0) | (rne_bf16(o1) << 16);
        yp2[n * 32 + c]  = (unsigned short)rne_bf16(o2);
    }
}

__global__ __launch_bounds__(256) void f_coef(const int* __restrict__ row, const int* __restrict__ col,
                                              const int* __restrict__ eslot,
                                              const float* __restrict__ aR, const float* __restrict__ aC,
                                              const float* __restrict__ wR, const float* __restrict__ wC,
                                              float4* __restrict__ meta, float* __restrict__ deg) {
    int e = blockIdx.x * 256 + threadIdx.x;
    if (e >= E0) return;
    int u = row[e], v = col[e];
    float a_e = tanhf(aR[u] + aC[v]);
    float a_r = tanhf(aR[v] + aC[u]);
    float wd_e = sigmoidf(wR[u] + wC[v]);
    float wd_r = sigmoidf(wR[v] + wC[u]);
    float w = wd_e * wd_r;
    float w2 = w * w;
    float ie = 1.0f / (1.0f + a_e * a_e), ir = 1.0f / (1.0f + a_r * a_r);
    float ce = (1.0f - a_e * a_e) * ie, se = 2.0f * a_e * ie;
    float cr = (1.0f - a_r * a_r) * ir, sr = 2.0f * a_r * ir;
    float C = ce * cr + se * sr;
    float S = ce * sr - se * cr;
    meta[eslot[e]]      = make_float4(C,  S, w2, __int_as_float(v));
    meta[eslot[e + E0]] = make_float4(C, -S, w2, __int_as_float(u));
    atomicAdd(&deg[u], w2);
    atomicAdd(&deg[v], w2);
}

__global__ __launch_bounds__(256) void f_dinv(const float* __restrict__ deg, float* __restrict__ dinv) {
    int n = blockIdx.x * 256 + threadIdx.x;
    if (n >= NN) return;
    float d = deg[n];
    dinv[n] = d > 0.0f ? rsqrtf(fmaxf(d, 1e-30f)) : 0.0f;
}

__global__ __launch_bounds__(256) void f_gather(const int* __restrict__ start, const int* __restrict__ cnt,
                                                const float4* __restrict__ meta,
                                                const float* __restrict__ dinv,
                                                const unsigned* __restrict__ yp01,
                                                const unsigned short* __restrict__ yp2,
                                                const float* __restrict__ eps,
                                                int layer, float* __restrict__ xc) {
    int tid = threadIdx.x;
    int node = tid >> 5, c = tid & 31;
    int n = blockIdx.x * 8 + node;
    if (n >= NN) return;
    int s0 = start[n], ec = cnt[n];
    float du = dinv[n];
    float acc0 = 0, acc1 = 0, acc2 = 0;
    for (int bs = 0; bs < ec; bs += 32) {
        int nb2 = min(32, ec - bs);
        float CC = 0, SS = 0, cnl = 0;
        int vj = 0;
        if (c < nb2) {
            float4 mt = meta[s0 + bs + c];
            vj = __float_as_int(mt.w);
            cnl = mt.z * du * dinv[vj];
            CC = cnl * mt.x;
            SS = cnl * mt.y;
        }
        for (int j = 0; j < nb2; ++j) {
            float Cj = __shfl(CC, j, 32);
            float Sj = __shfl(SS, j, 32);
            float cj = __shfl(cnl, j, 32);
            int v = __shfl(vj, j, 32);
            unsigned u01 = yp01[v * 32 + c];
            unsigned u2v = (unsigned)yp2[v * 32 + c];
            float y0 = __uint_as_float(u01 << 16);
            float y1 = __uint_as_float(u01 & 0xffff0000u);
            float y2 = __uint_as_float(u2v << 16);
            acc0 = fmaf(Cj, y0, acc0);
            acc0 = fmaf(-Sj, y1, acc0);
            acc1 = fmaf(Sj, y0, acc1);
            acc1 = fmaf(Cj, y1, acc1);
            acc2 = fmaf(cj, y2, acc2);
        }
    }
    float diag = du > 0.0f ? 1.0f : 0.0f;
    unsigned u01 = yp01[n * 32 + c];
    unsigned u2v = (unsigned)yp2[n * 32 + c];
    float oy0 = __uint_as_float(u01 << 16);
    float oy1 = __uint_as_float(u01 & 0xffff0000u);
    float oy2 = __uint_as_float(u2v << 16);
    float c0 = 1.0f + tanhf(eps[layer * 3 + 0]);
    float c1 = 1.0f + tanhf(eps[layer * 3 + 1]);
    float c2 = 1.0f + tanhf(eps[layer * 3 + 2]);
    int base = n * 96 + c;
    float z0 = eluf(diag * oy0 - acc0);
    float z1 = eluf(diag * oy1 - acc1);
    float z2 = eluf(diag * oy2 - acc2);
    xc[base]      = c0 * xc[base]      - z0;
    xc[base + 32] = c1 * xc[base + 32] - z1;
    xc[base + 64] = c2 * xc[base + 64] - z2;
}

extern "C" void kernel_launch(void* const* d_in, const int* in_sizes, int n_in,
                              void* d_out, int out_size, void* d_ws, size_t ws_size,
                              hipStream_t stream) {
    Params p;
    p.x   = (const float*)d_in[0];
    p.ei  = (const int*)d_in[1];
    p.W1  = (const float*)d_in[2];
    p.b1  = (const float*)d_in[3];
    p.W2  = (const float*)d_in[4];
    p.b2  = (const float*)d_in[5];
    p.Wl  = (const float*)d_in[6];
    p.Wr  = (const float*)d_in[7];
    p.eps = (const float*)d_in[8];
    p.Wsh = (const float*)d_in[9];
    p.Wwt = (const float*)d_in[10];
    p.out = (float*)d_out;

    char* pc = (char*)d_ws;
    p.xc    = (float*)pc;            pc += (size_t)NN * 96 * 4;
    p.meta  = (float4*)pc;           pc += (size_t)E2 * 16;
    p.yp01  = (unsigned*)pc;         pc += (size_t)NN * 32 * 4;
    p.yp2   = (unsigned short*)pc;   pc += (size_t)NN * 32 * 2;
    pc = (char*)(((size_t)pc + 15) & ~(size_t)15);
    p.aR    = (float*)pc;            pc += (size_t)NN * 4;
    p.aC    = (float*)pc;            pc += (size_t)NN * 4;
    p.wR    = (float*)pc;            pc += (size_t)NN * 4;
    p.wC    = (float*)pc;            pc += (size_t)NN * 4;
    p.deg   = (float*)pc;            pc += (size_t)NN * 4;
    p.dinv  = (float*)pc;            pc += (size_t)NN * 4;
    p.Wl_n  = (float*)pc;            pc += 32 * 4;
    p.Wr_n  = (float*)pc;            pc += 2048 * 4;
    p.cnt   = (int*)pc;              pc += (size_t)NN * 4;
    p.start = (int*)pc;              pc += (size_t)NN * 4;
    p.fill  = (int*)pc;              pc += (size_t)NN * 4;
    p.eslot = (int*)pc;              pc += (size_t)E2 * 4;
    p.bsum  = (int*)pc;              pc += 256 * 4;
    p.bofs  = (int*)pc;              pc += 256 * 4;
    p.w1hi  = (unsigned short*)pc;   pc += 96 * 128 * 2;
    p.w1lo  = (unsigned short*)pc;   pc += 96 * 128 * 2;
    p.w2hi  = (unsigned short*)pc;   pc += 32 * 96 * 2;
    p.w2lo  = (unsigned short*)pc;   pc += 32 * 96 * 2;

    // size the cooperative grid from the runtime's own occupancy model
    int occ = 0;
    hipError_t qerr = hipOccupancyMaxActiveBlocksPerMultiprocessor(&occ, (const void*)k_mega, 256, 0);
    int nCU = 256;
    {
        hipDeviceProp_t prop;
        int dev = 0;
        if (hipGetDevice(&dev) == hipSuccess && hipGetDeviceProperties(&prop, dev) == hipSuccess)
            nCU = prop.multiProcessorCount;
    }
    long gridN = (qerr == hipSuccess && occ > 0) ? (long)occ * nCU : 0;
    if (gridN > 2048) gridN = 2048;

    hipError_t lerr = hipErrorUnknown;
    if (gridN >= 3) {
        void* args[] = { &p };
        lerr = hipLaunchCooperativeKernel((void*)k_mega, dim3((unsigned)gridN), dim3(256), args, 0, stream);
    }
    if (lerr != hipSuccess) {
        // fallback: proven multi-kernel pipeline
        const int NB  = (NN + 255) / 256;
        const int EB  = (E2 + 255) / 256;
        const int EB0 = (E0 + 255) / 256;
        f_splitw<<<(96 * 128 + 255) / 256, 256, 0, stream>>>(p.W1, 96 * 128, p.w1hi, p.w1lo);
        f_splitw<<<(32 * 96 + 255) / 256, 256, 0, stream>>>(p.W2, 32 * 96, p.w2hi, p.w2lo);
        f_gemm<128, 96, true><<<NTILES, 256, 0, stream>>>(p.x, p.w1hi, p.w1lo, p.b1, p.xc);
        f_spectral<<<2, 256, 0, stream>>>(p.Wl, p.Wr, p.Wl_n, p.Wr_n);
        f_zero<<<NB, 256, 0, stream>>>(p.cnt, p.fill, p.deg);
        f_hist<<<EB, 256, 0, stream>>>(p.ei, p.cnt);
        f_scan1<<<NB, 256, 0, stream>>>(p.cnt, p.start, p.bsum);
        f_scan2<<<1, 256, 0, stream>>>(p.bsum, p.bofs, NB);
        f_scan3<<<NB, 256, 0, stream>>>(p.start, p.bofs);
        f_fill<<<EB, 256, 0, stream>>>(p.ei, p.start, p.fill, p.eslot);
        for (int l = 0; l < 2; ++l) {
            f_y8<<<NGROUPS, 256, 0, stream>>>(p.xc, p.Wl_n + l * 9, p.Wr_n + l * 1024, p.Wsh, p.Wwt, l,
                                              p.yp01, p.yp2, p.aR, p.aC, p.wR, p.wC, p.deg);
            f_coef<<<EB0, 256, 0, stream>>>(p.ei, p.ei + E2, p.eslot, p.aR, p.aC, p.wR, p.wC, p.meta, p.deg);
            f_dinv<<<NB, 256, 0, stream>>>(p.deg, p.dinv);
            f_gather<<<NGROUPS, 256, 0, stream>>>(p.start, p.cnt, p.meta, p.dinv,
                                                  p.yp01, p.yp2, p.eps, l, p.xc);
        }
        f_gemm<96, 32, false><<<NTILES, 256, 0, stream>>>(p.xc, p.w2hi, p.w2lo, p.b2, p.out);
    }
}

// Round 8
// 357.057 us; speedup vs baseline: 2.8175x; 2.8175x over previous
//
#include <hip/hip_runtime.h>

#define NN 50000
#define E0 200000
#define E2 400000
#define NGROUPS ((NN + 7) / 8)      // 6250
#define NCHUNK  ((NN + 255) / 256)  // 196
#define NTILES  ((NN + 63) / 64)    // 782

typedef __attribute__((ext_vector_type(8))) short short8;
typedef __attribute__((ext_vector_type(4))) float f32x4;

__device__ __forceinline__ float eluf(float x) { return x > 0.0f ? x : expm1f(x); }
__device__ __forceinline__ float sigmoidf(float x) { return 1.0f / (1.0f + expf(-x)); }
__device__ __forceinline__ unsigned rne_bf16(float x) {
    unsigned u = __float_as_uint(x);
    return (u + 0x7fffu + ((u >> 16) & 1u)) >> 16;
}

// ---------------- setup: weight split + spectral norm + zero cnt/fill/deg (1 dispatch)
__global__ __launch_bounds__(256) void k_setup(const float* __restrict__ W1, const float* __restrict__ W2,
                                               const float* __restrict__ Wl_in, const float* __restrict__ Wr_in,
                                               float* __restrict__ Wl_out, float* __restrict__ Wr_out,
                                               unsigned short* __restrict__ w1hi, unsigned short* __restrict__ w1lo,
                                               unsigned short* __restrict__ w2hi, unsigned short* __restrict__ w2lo,
                                               int* __restrict__ cnt, int* __restrict__ fill,
                                               float* __restrict__ deg) {
    __shared__ float W[32 * 33];
    __shared__ float us[32], vs[32], tmp[32];
    __shared__ float scal;
    int t = threadIdx.x;
    if (blockIdx.x < 2) {
        int l = blockIdx.x;
        for (int i = t; i < 1024; i += 256) W[(i >> 5) * 33 + (i & 31)] = Wr_in[l * 1024 + i];
        if (t < 32) us[t] = 0.17677669529663688f;
        __syncthreads();
        for (int it = 0; it < 20; ++it) {
            if (t < 32) { float a = 0; for (int r = 0; r < 32; ++r) a = fmaf(W[r * 33 + t], us[r], a); tmp[t] = a; }
            __syncthreads();
            if (t == 0) { float s = 0; for (int c = 0; c < 32; ++c) s += tmp[c] * tmp[c]; scal = 1.0f / (sqrtf(s) + 1e-12f); }
            __syncthreads();
            if (t < 32) vs[t] = tmp[t] * scal;
            __syncthreads();
            if (t < 32) { float a = 0; for (int c = 0; c < 32; ++c) a = fmaf(W[t * 33 + c], vs[c], a); tmp[t] = a; }
            __syncthreads();
            if (t == 0) { float s = 0; for (int r = 0; r < 32; ++r) s += tmp[r] * tmp[r]; scal = 1.0f / (sqrtf(s) + 1e-12f); }
            __syncthreads();
            if (t < 32) us[t] = tmp[t] * scal;
            __syncthreads();
        }
        if (t < 32) { float a = 0; for (int r = 0; r < 32; ++r) a = fmaf(W[r * 33 + t], us[r], a); tmp[t] = a; }
        __syncthreads();
        if (t == 0) {
            float s = 0; for (int c = 0; c < 32; ++c) s += tmp[c] * tmp[c];
            scal = (sqrtf(s) + 1e-12f) / s;   // 1/sigma
        }
        __syncthreads();
        for (int i = t; i < 1024; i += 256) Wr_out[l * 1024 + i] = W[(i >> 5) * 33 + (i & 31)] * scal;
        if (t == 0) {
            float M[9];
            for (int i = 0; i < 9; ++i) M[i] = Wl_in[l * 9 + i];
            float u[3] = {0.5773502691896258f, 0.5773502691896258f, 0.5773502691896258f};
            float v[3], u2[3];
            for (int it = 0; it < 20; ++it) {
                float s = 0;
                for (int c = 0; c < 3; ++c) { v[c] = M[c] * u[0] + M[3 + c] * u[1] + M[6 + c] * u[2]; s += v[c] * v[c]; }
                float inv = 1.0f / (sqrtf(s) + 1e-12f);
                for (int c = 0; c < 3; ++c) v[c] *= inv;
                s = 0;
                for (int r = 0; r < 3; ++r) { u2[r] = M[r * 3] * v[0] + M[r * 3 + 1] * v[1] + M[r * 3 + 2] * v[2]; s += u2[r] * u2[r]; }
                inv = 1.0f / (sqrtf(s) + 1e-12f);
                for (int r = 0; r < 3; ++r) u[r] = u2[r] * inv;
            }
            float s = 0;
            for (int c = 0; c < 3; ++c) { v[c] = M[c] * u[0] + M[3 + c] * u[1] + M[6 + c] * u[2]; s += v[c] * v[c]; }
            float inv = (sqrtf(s) + 1e-12f) / s;
            for (int i = 0; i < 9; ++i) Wl_out[l * 9 + i] = M[i] * inv;
        }
    } else {
        int base = (blockIdx.x - 2) * 256 + t;
        int stride = (gridDim.x - 2) * 256;
        for (int i = base; i < 96 * 128; i += stride) {
            float v = W1[i];
            unsigned h = rne_bf16(v);
            w1hi[i] = (unsigned short)h;
            w1lo[i] = (unsigned short)rne_bf16(v - __uint_as_float(h << 16));
        }
        for (int i = base; i < 32 * 96; i += stride) {
            float v = W2[i];
            unsigned h = rne_bf16(v);
            w2hi[i] = (unsigned short)h;
            w2lo[i] = (unsigned short)rne_bf16(v - __uint_as_float(h << 16));
        }
        for (int i = base; i < NN; i += stride) { cnt[i] = 0; fill[i] = 0; deg[i] = 0.0f; }
    }
}

// ---------------- MFMA GEMM (r5-proven): out = act(X[M,K] @ W[N,K]^T + b), split-bf16
// Optional tail: edge histogram (fused into lin1's dispatch)
template<int K, int N, bool ELU, bool HIST>
__global__ __launch_bounds__(256) void k_gemm(const float* __restrict__ X,
                                              const unsigned short* __restrict__ Whi,
                                              const unsigned short* __restrict__ Wlo,
                                              const float* __restrict__ bias,
                                              float* __restrict__ out,
                                              const int* __restrict__ row, int* __restrict__ cnt) {
    constexpr int KP = K + 8;
    constexpr int NT = N / 16;
    constexpr int KS = K / 32;
    __shared__ __align__(16) unsigned short whi[N * KP];
    __shared__ __align__(16) unsigned short wlo[N * KP];
    int tid = threadIdx.x;
    for (int i = tid; i < N * K / 2; i += 256) {
        unsigned vh = ((const unsigned*)Whi)[i];
        unsigned vl = ((const unsigned*)Wlo)[i];
        int e = i * 2, r = e / K, c = e % K;
        *(unsigned*)&whi[r * KP + c] = vh;
        *(unsigned*)&wlo[r * KP + c] = vl;
    }
    __syncthreads();
    int wave = tid >> 6, lane = tid & 63;
    int quad = lane >> 4, r16 = lane & 15;
    long m = (long)blockIdx.x * 64 + wave * 16 + r16;
    long mc = m < NN ? m : (NN - 1);      // clamp OOB A-loads; stores guarded
    const float* xrow = X + mc * K + quad * 8;
    f32x4 acc[NT];
#pragma unroll
    for (int t = 0; t < NT; ++t) acc[t] = (f32x4){0.f, 0.f, 0.f, 0.f};
#pragma unroll
    for (int ks = 0; ks < KS; ++ks) {
        const float4* xp = (const float4*)(xrow + ks * 32);
        float4 p0 = xp[0], p1 = xp[1];
        float xv[8] = {p0.x, p0.y, p0.z, p0.w, p1.x, p1.y, p1.z, p1.w};
        short8 a_hi, a_lo;
#pragma unroll
        for (int j = 0; j < 8; ++j) {
            unsigned h = rne_bf16(xv[j]);
            a_hi[j] = (short)h;
            a_lo[j] = (short)rne_bf16(xv[j] - __uint_as_float(h << 16));
        }
#pragma unroll
        for (int t = 0; t < NT; ++t) {
            int ro = (t * 16 + r16) * KP + ks * 32 + quad * 8;
            short8 bh = *(const short8*)&whi[ro];
            short8 bl = *(const short8*)&wlo[ro];
            acc[t] = __builtin_amdgcn_mfma_f32_16x16x32_bf16(a_hi, bh, acc[t], 0, 0, 0);
            acc[t] = __builtin_amdgcn_mfma_f32_16x16x32_bf16(a_lo, bh, acc[t], 0, 0, 0);
            acc[t] = __builtin_amdgcn_mfma_f32_16x16x32_bf16(a_hi, bl, acc[t], 0, 0, 0);
        }
    }
    // C/D layout: col = lane&15, row = quad*4 + reg [m89-verified]
    long mbase = (long)blockIdx.x * 64 + wave * 16 + quad * 4;
#pragma unroll
    for (int t = 0; t < NT; ++t) {
        float b = bias[t * 16 + r16];
#pragma unroll
        for (int rr = 0; rr < 4; ++rr) {
            long mm = mbase + rr;
            if (mm < NN) {
                float v = acc[t][rr] + b;
                if (ELU) v = eluf(v);
                out[mm * N + t * 16 + r16] = v;
            }
        }
    }
    if (HIST) {
        for (int e = blockIdx.x * 256 + tid; e < E2; e += gridDim.x * 256)
            atomicAdd(&cnt[row[e]], 1);
    }
}

// ---------------- CSR: per-chunk scan, chunk-sum scan; offsets folded into consumers
__global__ __launch_bounds__(256) void k_scan1(const int* __restrict__ cnt, int* __restrict__ start,
                                               int* __restrict__ bsum) {
    __shared__ int s[256];
    int b = blockIdx.x, t = threadIdx.x;
    int i = b * 256 + t;
    int v = (i < NN) ? cnt[i] : 0;
    s[t] = v;
    __syncthreads();
    for (int off = 1; off < 256; off <<= 1) {
        int add = (t >= off) ? s[t - off] : 0;
        __syncthreads();
        s[t] += add;
        __syncthreads();
    }
    if (i < NN) start[i] = s[t] - v;      // chunk-local exclusive
    if (t == 255) bsum[b] = s[t];
}
__global__ __launch_bounds__(256) void k_scan2(const int* __restrict__ bsum, int* __restrict__ bofs, int nb) {
    __shared__ int s[256];
    int t = threadIdx.x;
    int v = (t < nb) ? bsum[t] : 0;
    s[t] = v;
    __syncthreads();
    for (int off = 1; off < 256; off <<= 1) {
        int add = (t >= off) ? s[t - off] : 0;
        __syncthreads();
        s[t] += add;
        __syncthreads();
    }
    if (t < nb) bofs[t] = s[t] - v;
}
__global__ __launch_bounds__(256) void k_fill(const int* __restrict__ row, const int* __restrict__ start,
                                              const int* __restrict__ bofs,
                                              int* __restrict__ fill, int* __restrict__ eslot) {
    int e = blockIdx.x * 256 + threadIdx.x;
    if (e >= E2) return;
    int u = row[e];
    eslot[e] = start[u] + bofs[u >> 8] + atomicAdd(&fill[u], 1);
}

// ---------------- y (packed bf16 uint2) + node projections; zeroes deg for this layer
__global__ __launch_bounds__(256) void k_y8(const float* __restrict__ xc,
                                            const float* __restrict__ Wl, const float* __restrict__ Wr,
                                            const float* __restrict__ Wsh, const float* __restrict__ Wwt,
                                            int layer, uint2* __restrict__ yp,
                                            float* __restrict__ aR, float* __restrict__ aC,
                                            float* __restrict__ wR, float* __restrict__ wC,
                                            float* __restrict__ deg) {
    __shared__ float wrs[32 * 33];
    __shared__ float wls[9];
    __shared__ float xcs[8][96];
    __shared__ float ws1[192], wt[192];
    int tid = threadIdx.x;
    int n0 = blockIdx.x * 8;
    if (tid < 8) { int nz = n0 + tid; if (nz < NN) deg[nz] = 0.0f; }
    for (int i = tid; i < 1024; i += 256) wrs[(i >> 5) * 33 + (i & 31)] = Wr[i];
    if (tid < 9) wls[tid] = Wl[tid];
    if (tid < 192) {
        ws1[tid] = Wsh[(layer * 3 + 1) * 192 + tid];  // only row 1 of W_sheaf survives Cayley (D=2)
        wt[tid]  = Wwt[layer * 192 + tid];
    }
    for (int i = tid; i < 768; i += 256) {
        int n = n0 + i / 96;
        xcs[i / 96][i % 96] = (n < NN) ? xc[n * 96 + i % 96] : 0.0f;
    }
    __syncthreads();
    int node = tid >> 5, c = tid & 31;
    int n = n0 + node;
    float a1 = 0, a2 = 0, a3 = 0, a4 = 0;
#pragma unroll
    for (int j = 0; j < 3; ++j) {
        int k = j * 32 + c;
        float xv = xcs[node][k];
        a1 = fmaf(xv, ws1[k], a1);
        a2 = fmaf(xv, ws1[96 + k], a2);
        a3 = fmaf(xv, wt[k], a3);
        a4 = fmaf(xv, wt[96 + k], a4);
    }
#pragma unroll
    for (int off = 16; off; off >>= 1) {
        a1 += __shfl_xor(a1, off);
        a2 += __shfl_xor(a2, off);
        a3 += __shfl_xor(a3, off);
        a4 += __shfl_xor(a4, off);
    }
    if (c == 0 && n < NN) { aR[n] = a1; aC[n] = a2; wR[n] = a3; wC[n] = a4; }
    if (n < NN) {
        float t0 = 0, t1 = 0, t2 = 0;
        const float* wr = &wrs[c * 33];
        const float* xr = xcs[node];
#pragma unroll
        for (int h = 0; h < 32; ++h) {
            float w = wr[h];
            t0 = fmaf(xr[h], w, t0);
            t1 = fmaf(xr[32 + h], w, t1);
            t2 = fmaf(xr[64 + h], w, t2);
        }
        float o0 = wls[0] * t0 + wls[1] * t1 + wls[2] * t2;
        float o1 = wls[3] * t0 + wls[4] * t1 + wls[5] * t2;
        float o2 = wls[6] * t0 + wls[7] * t1 + wls[8] * t2;
        yp[n * 32 + c] = make_uint2(rne_bf16(o0) | (rne_bf16(o1) << 16), rne_bf16(o2));
    }
}

// ---------------- per-edge coefficients (E0 only; reverse via T^T symmetry) + degree
__global__ __launch_bounds__(256) void k_coef(const int* __restrict__ row, const int* __restrict__ col,
                                              const int* __restrict__ eslot,
                                              const float* __restrict__ aR, const float* __restrict__ aC,
                                              const float* __restrict__ wR, const float* __restrict__ wC,
                                              float4* __restrict__ meta, float* __restrict__ deg) {
    int e = blockIdx.x * 256 + threadIdx.x;
    if (e >= E0) return;
    int u = row[e], v = col[e];
    float a_e = tanhf(aR[u] + aC[v]);
    float a_r = tanhf(aR[v] + aC[u]);
    float wd_e = sigmoidf(wR[u] + wC[v]);
    float wd_r = sigmoidf(wR[v] + wC[u]);
    float w = wd_e * wd_r;
    float w2 = w * w;
    float ie = 1.0f / (1.0f + a_e * a_e), ir = 1.0f / (1.0f + a_r * a_r);
    float ce = (1.0f - a_e * a_e) * ie, se = 2.0f * a_e * ie;
    float cr = (1.0f - a_r * a_r) * ir, sr = 2.0f * a_r * ir;
    float C = ce * cr + se * sr;   // T_e = Q_e^T Q_rev ; T_rev = T_e^T -> (C,-S)
    float S = ce * sr - se * cr;
    meta[eslot[e]]      = make_float4(C,  S, w2, __int_as_float(v));
    meta[eslot[e + E0]] = make_float4(C, -S, w2, __int_as_float(u));
    atomicAdd(&deg[u], w2);
    atomicAdd(&deg[v], w2);
}

__global__ __launch_bounds__(256) void k_dinv(const float* __restrict__ deg, float* __restrict__ dinv) {
    int n = blockIdx.x * 256 + threadIdx.x;
    if (n >= NN) return;
    float d = deg[n];
    dinv[n] = d > 0.0f ? rsqrtf(fmaxf(d, 1e-30f)) : 0.0f;
}

// ---------------- gather + residual update (8B packed y, slot-ordered meta, shfl broadcast)
__global__ __launch_bounds__(256) void k_gather(const int* __restrict__ start, const int* __restrict__ bofs,
                                                const int* __restrict__ cnt,
                                                const float4* __restrict__ meta,
                                                const float* __restrict__ dinv,
                                                const uint2* __restrict__ yp,
                                                const float* __restrict__ eps,
                                                int layer, float* __restrict__ xc) {
    int tid = threadIdx.x;
    int node = tid >> 5, c = tid & 31;
    int n = blockIdx.x * 8 + node;
    if (n >= NN) return;
    int s0 = start[n] + bofs[n >> 8], ec = cnt[n];
    float du = dinv[n];
    float acc0 = 0, acc1 = 0, acc2 = 0;
    for (int bs = 0; bs < ec; bs += 32) {
        int nb2 = min(32, ec - bs);
        float CC = 0, SS = 0, cnl = 0;
        int vj = 0;
        if (c < nb2) {
            float4 mt = meta[s0 + bs + c];
            vj = __float_as_int(mt.w);
            cnl = mt.z * du * dinv[vj];
            CC = cnl * mt.x;
            SS = cnl * mt.y;
        }
        for (int j = 0; j < nb2; ++j) {
            float Cj = __shfl(CC, j, 32);
            float Sj = __shfl(SS, j, 32);
            float cj = __shfl(cnl, j, 32);
            int v = __shfl(vj, j, 32);
            uint2 uy = yp[v * 32 + c];
            float y0 = __uint_as_float(uy.x << 16);
            float y1 = __uint_as_float(uy.x & 0xffff0000u);
            float y2 = __uint_as_float(uy.y << 16);
            acc0 = fmaf(Cj, y0, acc0);
            acc0 = fmaf(-Sj, y1, acc0);
            acc1 = fmaf(Sj, y0, acc1);
            acc1 = fmaf(Cj, y1, acc1);
            acc2 = fmaf(cj, y2, acc2);
        }
    }
    float diag = du > 0.0f ? 1.0f : 0.0f;
    uint2 uy = yp[n * 32 + c];
    float oy0 = __uint_as_float(uy.x << 16);
    float oy1 = __uint_as_float(uy.x & 0xffff0000u);
    float oy2 = __uint_as_float(uy.y << 16);
    float c0 = 1.0f + tanhf(eps[layer * 3 + 0]);
    float c1 = 1.0f + tanhf(eps[layer * 3 + 1]);
    float c2 = 1.0f + tanhf(eps[layer * 3 + 2]);
    int base = n * 96 + c;
    float z0 = eluf(diag * oy0 - acc0);
    float z1 = eluf(diag * oy1 - acc1);
    float z2 = eluf(diag * oy2 - acc2);
    xc[base]      = c0 * xc[base]      - z0;
    xc[base + 32] = c1 * xc[base + 32] - z1;
    xc[base + 64] = c2 * xc[base + 64] - z2;
}

extern "C" void kernel_launch(void* const* d_in, const int* in_sizes, int n_in,
                              void* d_out, int out_size, void* d_ws, size_t ws_size,
                              hipStream_t stream) {
    const float* x     = (const float*)d_in[0];
    const int*   ei    = (const int*)d_in[1];
    const float* W1    = (const float*)d_in[2];
    const float* b1    = (const float*)d_in[3];
    const float* W2    = (const float*)d_in[4];
    const float* b2    = (const float*)d_in[5];
    const float* Wl    = (const float*)d_in[6];
    const float* Wr    = (const float*)d_in[7];
    const float* eps   = (const float*)d_in[8];
    const float* Wsh   = (const float*)d_in[9];
    const float* Wwt   = (const float*)d_in[10];
    float* out = (float*)d_out;
    const int* row = ei;        // edge_index[0]
    const int* col = ei + E2;   // edge_index[1]

    char* pc = (char*)d_ws;
    float* xc    = (float*)pc;          pc += (size_t)NN * 96 * 4;
    float4* meta = (float4*)pc;         pc += (size_t)E2 * 16;
    uint2* yp    = (uint2*)pc;          pc += (size_t)NN * 32 * 8;
    float* aR    = (float*)pc;          pc += (size_t)NN * 4;
    float* aC    = (float*)pc;          pc += (size_t)NN * 4;
    float* wRp   = (float*)pc;          pc += (size_t)NN * 4;
    float* wCp   = (float*)pc;          pc += (size_t)NN * 4;
    float* deg   = (float*)pc;          pc += (size_t)NN * 4;
    float* dinv  = (float*)pc;          pc += (size_t)NN * 4;
    float* Wl_n  = (float*)pc;          pc += 32 * 4;
    float* Wr_n  = (float*)pc;          pc += 2048 * 4;
    int* cnt     = (int*)pc;            pc += (size_t)NN * 4;
    int* start   = (int*)pc;            pc += (size_t)NN * 4;
    int* fill    = (int*)pc;            pc += (size_t)NN * 4;
    int* eslot   = (int*)pc;            pc += (size_t)E2 * 4;
    int* bsum    = (int*)pc;            pc += 256 * 4;
    int* bofs    = (int*)pc;            pc += 256 * 4;
    unsigned short* w1hi = (unsigned short*)pc; pc += 96 * 128 * 2;
    unsigned short* w1lo = (unsigned short*)pc; pc += 96 * 128 * 2;
    unsigned short* w2hi = (unsigned short*)pc; pc += 32 * 96 * 2;
    unsigned short* w2lo = (unsigned short*)pc; pc += 32 * 96 * 2;

    const int EB = (E2 + 255) / 256;

    // 14 dispatches total
    k_setup<<<66, 256, 0, stream>>>(W1, W2, Wl, Wr, Wl_n, Wr_n,
                                    w1hi, w1lo, w2hi, w2lo, cnt, fill, deg);
    k_gemm<128, 96, true, true><<<NTILES, 256, 0, stream>>>(x, w1hi, w1lo, b1, xc, row, cnt);
    k_scan1<<<NCHUNK, 256, 0, stream>>>(cnt, start, bsum);
    k_scan2<<<1, 256, 0, stream>>>(bsum, bofs, NCHUNK);
    k_fill<<<EB, 256, 0, stream>>>(row, start, bofs, fill, eslot);
    for (int l = 0; l < 2; ++l) {
        k_y8<<<NGROUPS, 256, 0, stream>>>(xc, Wl_n + l * 9, Wr_n + l * 1024, Wsh, Wwt, l,
                                          yp, aR, aC, wRp, wCp, deg);
        k_coef<<<(E0 + 255) / 256, 256, 0, stream>>>(row, col, eslot, aR, aC, wRp, wCp, meta, deg);
        k_dinv<<<NCHUNK, 256, 0, stream>>>(deg, dinv);
        k_gather<<<NGROUPS, 256, 0, stream>>>(start, bofs, cnt, meta, dinv, yp, eps, l, xc);
    }
    k_gemm<96, 32, false, false><<<NTILES, 256, 0, stream>>>(xc, w2hi, w2lo, b2, out, nullptr, nullptr);
}